// Round 4
// baseline (559.384 us; speedup 1.0000x reference)
//
#include <hip/hip_runtime.h>
#include <hip/hip_bf16.h>
#include <stdint.h>

typedef __bf16 bf16x8 __attribute__((ext_vector_type(8)));
typedef float f32x4 __attribute__((ext_vector_type(4)));

// ---- helpers ------------------------------------------------------------

__device__ inline void gload_lds16(const void* g, void* lds) {
  // async global->LDS, 16B per lane. LDS dest is wave-uniform base;
  // HW writes base + lane*16. Global src is per-lane.
  __builtin_amdgcn_global_load_lds(
      (const __attribute__((address_space(1))) uint32_t*)(uintptr_t)g,
      (__attribute__((address_space(3))) uint32_t*)(uintptr_t)lds,
      16, 0, 0);
}

__device__ inline short f2bf(float f) {
  union { float f; uint32_t u; } x; x.f = f;
  uint32_t u = x.u;
  u += 0x7fffu + ((u >> 16) & 1u);   // RNE
  return (short)(u >> 16);
}

#define BAR() do { asm volatile("" ::: "memory"); \
                   __builtin_amdgcn_s_barrier();  \
                   asm volatile("" ::: "memory"); } while (0)

// ---- fp32 -> bf16 convert (vectorized) ----------------------------------

__global__ __launch_bounds__(256) void cvt_f32_bf16(
    const float* __restrict__ in, short* __restrict__ out, int n4) {
  int i = blockIdx.x * 256 + threadIdx.x;
  if (i < n4) {
    float4 v = reinterpret_cast<const float4*>(in)[i];
    short4 o;
    o.x = f2bf(v.x); o.y = f2bf(v.y); o.z = f2bf(v.z); o.w = f2bf(v.w);
    reinterpret_cast<short4*>(out)[i] = o;
  }
}

// ---- GEMM: C[M,N] = A[M,K] @ B[N,K]^T, bf16 in, fp32 acc ---------------
// Register read-ahead schedule, 1 barrier per K-tile.
// 256x256 tile, BK=64, 8 waves (2Mx4N), per-wave 128x64 = acc[8][4] of
// mfma_f32_16x16x32_bf16.
//
// LDS: 2 buffers x 4 half-tile slots x [128 rows x 64 k] bf16 = 128 KiB.
//   slot 0 (A0): A tile rows {0..63}u{128..191}   (per-wave m-frags 0-3)
//   slot 1 (A1): A tile rows {64..127}u{192..255} (m-frags 4-7)
//   slot 2 (B0): B rows for n-frags 0,1 of every wc
//   slot 3 (B1): B rows for n-frags 2,3 of every wc
//
// Per tile t (cur=t&1, nxt=cur^1):
//   S : stage all 4 half-tiles of t+1 -> buf[nxt]   (8 gloads)
//   R1: read a0q (8 ds_read_b128) + bq0 (4) from buf[cur]
//   R2: read a1q (8)
//   M1: m0-3 x n0-1 (16 MFMA)     <- waits only R1 (R2 stays in flight)
//   R3: read bq1 (4)
//   M2: m4-7 x n0-1               <- R2 landed under M1's shadow
//   M3: m0-3 x n2-3               <- R3 landed under M2's shadow
//   M4: m4-7 x n2-3
//   W : vmcnt(0) (stage loads had ~whole tile in flight, >= HBM latency)
//       + s_barrier  (publish t+1; also separates tile t's buf[cur] reads
//       from tile t+1's stages into buf[cur])
// Hazards: reads of buf[cur] lie between BAR(t-1)(publish) and BAR(t);
// stages into buf[nxt] are 1 barrier after tile t-1's last read of it.
// ds_reads cannot cross the asm "memory" barriers; MFMA sinking past the
// barrier is benign (register dataflow is compiler-guaranteed).
// EPI=0: bias+relu^2->bf16; EPI=1: bias->f32.

template <int EPI>
__global__ __launch_bounds__(512, 2) void gemm_bt(
    const short* __restrict__ A, const short* __restrict__ B,
    const float* __restrict__ bias, void* __restrict__ Cout,
    int M, int N, int K) {
  __shared__ __align__(16) short lds[2][4][128 * 64];

  const int tid  = threadIdx.x;
  const int wave = tid >> 6;
  const int lane = tid & 63;
  const int wr = wave >> 2;          // 0..1 -> M half (128 rows)
  const int wc = wave & 3;           // 0..3 -> N quarter (64 cols)
  const int fr = lane & 15, kq = lane >> 4;

  // T1: bijective XCD swizzle (nwg % 8 == 0), column-major in-chunk
  const int nwg = gridDim.x;
  const int w = (blockIdx.x & 7) * (nwg >> 3) + (blockIdx.x >> 3);
  const int gy = M >> 8;
  const int brow = w % gy;
  const int bcol = w / gy;

  f32x4 acc[8][4];
#pragma unroll
  for (int m = 0; m < 8; ++m)
#pragma unroll
    for (int n = 0; n < 4; ++n)
      acc[m][n] = (f32x4){0.f, 0.f, 0.f, 0.f};

  const int nk = K >> 6;             // K-tiles of 64

  // ---- T2 swizzle (within a 128x64 slot): granule g = r*8 + gc (16B
  // granules, 8/row), stored at P = g ^ (r&7). Involution; verified
  // 0 bank conflicts (round 3).
  int offA[4][2], offB[2][2];
#pragma unroll
  for (int m = 0; m < 4; ++m)
#pragma unroll
    for (int kk = 0; kk < 2; ++kk) {
      int r = wr * 64 + m * 16 + fr;
      int g = r * 8 + kk * 4 + kq;
      offA[m][kk] = (g ^ (r & 7)) * 16;
    }
#pragma unroll
  for (int n = 0; n < 2; ++n)
#pragma unroll
    for (int kk = 0; kk < 2; ++kk) {
      int r = wc * 32 + n * 16 + fr;
      int g = r * 8 + kk * 4 + kq;
      offB[n][kk] = (g ^ (r & 7)) * 16;
    }

  // ---- stage source: physical granule i in {tid, 512+tid} holds logical
  // gl = i ^ ((i>>3)&7); slot row r = gl>>3, col granule c = gl&7.
  const int i0 = tid;
  const int gl0 = i0 ^ ((i0 >> 3) & 7);
  const int r0 = gl0 >> 3, c0 = gl0 & 7;
  const size_t rstep = (size_t)128 * K;

  const short* pA[2];
  const short* pB[2];
  {
    const int rb0 = (r0 >> 5) * 64 + (r0 & 31);
#pragma unroll
    for (int h = 0; h < 2; ++h) {
      pA[h] = A + (size_t)(brow * 256 + h * 64 + r0) * K + c0 * 8;
      pB[h] = B + (size_t)(bcol * 256 + rb0 + h * 32) * K + c0 * 8;
    }
  }

  const int dst0 = wave * 512, dst1 = 4096 + wave * 512;  // shorts in slot

#define STAGE(p, buf, slot)                              \
  do {                                                   \
    short* base_ = &lds[buf][slot][0];                   \
    gload_lds16((p), base_ + dst0);                      \
    gload_lds16((p) + rstep, base_ + dst1);              \
    (p) += 64;                                           \
  } while (0)

  // ---- prologue: stage tile 0, publish.
  STAGE(pA[0], 0, 0);
  STAGE(pA[1], 0, 1);
  STAGE(pB[0], 0, 2);
  STAGE(pB[1], 0, 3);
  asm volatile("s_waitcnt vmcnt(0)" ::: "memory");
  BAR();

  bf16x8 a0q[4][2], a1q[4][2], bq0[2][2], bq1[2][2];

  for (int t = 0; t < nk; ++t) {
    const int cur = t & 1, nxt = cur ^ 1;
    const bool s1 = (t + 1) < nk;

    // S: stage all of tile t+1 (issue early; lands under this tile's MFMA)
    if (s1) {
      STAGE(pA[0], nxt, 0);
      STAGE(pA[1], nxt, 1);
      STAGE(pB[0], nxt, 2);
      STAGE(pB[1], nxt, 3);
    }

    const char* sA0 = (const char*)&lds[cur][0][0];
    const char* sA1 = (const char*)&lds[cur][1][0];
    const char* sB0 = (const char*)&lds[cur][2][0];
    const char* sB1 = (const char*)&lds[cur][3][0];

    // R1: operands for M1
#pragma unroll
    for (int m = 0; m < 4; ++m)
#pragma unroll
      for (int kk = 0; kk < 2; ++kk)
        a0q[m][kk] = *(const bf16x8*)(sA0 + offA[m][kk]);
#pragma unroll
    for (int n = 0; n < 2; ++n)
#pragma unroll
      for (int kk = 0; kk < 2; ++kk)
        bq0[n][kk] = *(const bf16x8*)(sB0 + offB[n][kk]);

    // R2: operands for M2 (in flight across M1)
#pragma unroll
    for (int m = 0; m < 4; ++m)
#pragma unroll
      for (int kk = 0; kk < 2; ++kk)
        a1q[m][kk] = *(const bf16x8*)(sA1 + offA[m][kk]);

    // M1: m0-3 x n0-1
    __builtin_amdgcn_s_setprio(1);
#pragma unroll
    for (int m = 0; m < 4; ++m)
#pragma unroll
      for (int n = 0; n < 2; ++n)
#pragma unroll
        for (int kk = 0; kk < 2; ++kk)
          acc[m][n] = __builtin_amdgcn_mfma_f32_16x16x32_bf16(
              a0q[m][kk], bq0[n][kk], acc[m][n], 0, 0, 0);
    __builtin_amdgcn_s_setprio(0);

    // R3: operands for M3 (in flight across M2)
#pragma unroll
    for (int n = 0; n < 2; ++n)
#pragma unroll
      for (int kk = 0; kk < 2; ++kk)
        bq1[n][kk] = *(const bf16x8*)(sB1 + offB[n][kk]);

    // M2: m4-7 x n0-1
    __builtin_amdgcn_s_setprio(1);
#pragma unroll
    for (int m = 0; m < 4; ++m)
#pragma unroll
      for (int n = 0; n < 2; ++n)
#pragma unroll
        for (int kk = 0; kk < 2; ++kk)
          acc[m + 4][n] = __builtin_amdgcn_mfma_f32_16x16x32_bf16(
              a1q[m][kk], bq0[n][kk], acc[m + 4][n], 0, 0, 0);
    __builtin_amdgcn_s_setprio(0);

    // M3: m0-3 x n2-3
    __builtin_amdgcn_s_setprio(1);
#pragma unroll
    for (int m = 0; m < 4; ++m)
#pragma unroll
      for (int n = 0; n < 2; ++n)
#pragma unroll
        for (int kk = 0; kk < 2; ++kk)
          acc[m][n + 2] = __builtin_amdgcn_mfma_f32_16x16x32_bf16(
              a0q[m][kk], bq1[n][kk], acc[m][n + 2], 0, 0, 0);
    __builtin_amdgcn_s_setprio(0);

    // M4: m4-7 x n2-3
    __builtin_amdgcn_s_setprio(1);
#pragma unroll
    for (int m = 0; m < 4; ++m)
#pragma unroll
      for (int n = 0; n < 2; ++n)
#pragma unroll
        for (int kk = 0; kk < 2; ++kk)
          acc[m + 4][n + 2] = __builtin_amdgcn_mfma_f32_16x16x32_bf16(
              a1q[m][kk], bq1[n][kk], acc[m + 4][n + 2], 0, 0, 0);
    __builtin_amdgcn_s_setprio(0);

    // W: single boundary sync per tile
    if (s1) {
      asm volatile("s_waitcnt vmcnt(0)" ::: "memory");
      BAR();
    }
  }

  // ---- epilogue: C/D layout col=lane&15, row=(lane>>4)*4+reg
  const int q = lane >> 4;
  if (EPI == 0) {
    short* C = (short*)Cout;
#pragma unroll
    for (int m = 0; m < 8; ++m) {
      const int row0 = brow * 256 + wr * 128 + m * 16 + q * 4;
#pragma unroll
      for (int n = 0; n < 4; ++n) {
        const int col = bcol * 256 + wc * 64 + n * 16 + fr;
        const float bv = bias[col];
#pragma unroll
        for (int j = 0; j < 4; ++j) {
          float v = acc[m][n][j] + bv;
          v = v > 0.f ? v * v : 0.f;   // squared ReLU
          C[(size_t)(row0 + j) * N + col] = f2bf(v);
        }
      }
    }
  } else {
    float* C = (float*)Cout;
#pragma unroll
    for (int m = 0; m < 8; ++m) {
      const int row0 = brow * 256 + wr * 128 + m * 16 + q * 4;
#pragma unroll
      for (int n = 0; n < 4; ++n) {
        const int col = bcol * 256 + wc * 64 + n * 16 + fr;
        const float bv = bias[col];
#pragma unroll
        for (int j = 0; j < 4; ++j)
          C[(size_t)(row0 + j) * N + col] = acc[m][n][j] + bv;
      }
    }
  }
#undef STAGE
}

// ---- launch -------------------------------------------------------------

extern "C" void kernel_launch(void* const* d_in, const int* in_sizes, int n_in,
                              void* d_out, int out_size, void* d_ws,
                              size_t ws_size, hipStream_t stream) {
  const float* x  = (const float*)d_in[0];
  const float* w1 = (const float*)d_in[1];
  const float* b1 = (const float*)d_in[2];
  const float* w2 = (const float*)d_in[3];
  const float* b2 = (const float*)d_in[4];
  float* out = (float*)d_out;

  const int H = in_sizes[2];            // 8192
  const int D = in_sizes[4];            // 2048
  const int M = in_sizes[0] / D;        // B*S = 8192

  // workspace layout (all bf16 as short):
  short* xb  = (short*)d_ws;                 // M*D
  short* w1b = xb  + (size_t)M * D;          // H*D
  short* w2b = w1b + (size_t)H * D;          // D*H
  short* act = w2b + (size_t)D * H;          // M*H

  {
    int n4 = (M * D) / 4;
    cvt_f32_bf16<<<(n4 + 255) / 256, 256, 0, stream>>>(x, xb, n4);
    n4 = (H * D) / 4;
    cvt_f32_bf16<<<(n4 + 255) / 256, 256, 0, stream>>>(w1, w1b, n4);
    n4 = (D * H) / 4;
    cvt_f32_bf16<<<(n4 + 255) / 256, 256, 0, stream>>>(w2, w2b, n4);
  }

  // GEMM1: [M,D] @ [H,D]^T -> sqrelu -> act[M,H] (bf16)
  gemm_bt<0><<<(M / 256) * (H / 256), 512, 0, stream>>>(
      xb, w1b, b1, (void*)act, M, H, D);
  // GEMM2: [M,H] @ [D,H]^T -> + b2 -> out[M,D] (f32)
  gemm_bt<1><<<(M / 256) * (D / 256), 512, 0, stream>>>(
      act, w2b, b2, (void*)out, M, D, H);
}